// Round 3
// baseline (592.897 us; speedup 1.0000x reference)
//
#include <hip/hip_runtime.h>
#include <stdint.h>

#define NN 100000      // nodes
#define EE 500000      // edges
#define HIDD 256
#define K1PAD 576      // 551 -> padded to 9 chunks of 64
#define LN_EPS 1e-5f

typedef short frag8 __attribute__((ext_vector_type(8)));     // raw 16b storage
typedef _Float16 half8 __attribute__((ext_vector_type(8)));  // 8 fp16 (4 VGPRs)
typedef float f32x4 __attribute__((ext_vector_type(4)));

__device__ __forceinline__ unsigned short f2h(float f) {
  // round-to-nearest-even f32 -> fp16 (v_cvt_f16_f32)
  _Float16 h = (_Float16)f;
  union { _Float16 hh; unsigned short us; } u; u.hh = h;
  return u.us;
}

__device__ __forceinline__ void g2l16(void* lds, const void* g) {
  __builtin_amdgcn_global_load_lds(
      (const __attribute__((address_space(1))) unsigned int*)g,
      (__attribute__((address_space(3))) unsigned int*)lds, 16, 0, 0);
}

// ---- prep: h (f32) -> fp16 ----
__global__ __launch_bounds__(256) void conv_h_kern(const float* __restrict__ h,
                                                   unsigned short* __restrict__ hb) {
  int i = (blockIdx.x * 256 + threadIdx.x) * 8;   // exact: N*HID = 25.6M = 12500*256*8
  float4 v0 = *(const float4*)(h + i);
  float4 v1 = *(const float4*)(h + i + 4);
  union { unsigned short us[8]; int4 v; } u;
  u.us[0] = f2h(v0.x); u.us[1] = f2h(v0.y); u.us[2] = f2h(v0.z); u.us[3] = f2h(v0.w);
  u.us[4] = f2h(v1.x); u.us[5] = f2h(v1.y); u.us[6] = f2h(v1.z); u.us[7] = f2h(v1.w);
  *(int4*)(hb + i) = u.v;
}

// ---- prep: swizzle weights into MFMA-fragment order (fp16) ----
// W1T_sw: [chunk k/64][kq (k%64)/8][n 0..255][j k%8], k>=551 zero.  147456 elems
// W2T_sw: [chunk][kq][n2 0..127][j]                                  32768 elems
// W3_sw : [kq k/8][o 0..15][j], o>=5 zero                            2048 elems
__global__ __launch_bounds__(256) void conv_w_kern(const float* __restrict__ W1,
                                                   const float* __restrict__ W2,
                                                   const float* __restrict__ W3,
                                                   unsigned short* __restrict__ w1sw,
                                                   unsigned short* __restrict__ w2sw,
                                                   unsigned short* __restrict__ w3sw) {
  int t = blockIdx.x * 256 + threadIdx.x;
  if (t < 147456) {
    int chunk = t >> 14, rem = t & 16383;
    int kq = rem >> 11, n = (rem >> 3) & 255, j = rem & 7;
    int k = (chunk << 6) + (kq << 3) + j;
    float v = (k < 551) ? W1[k * 256 + n] : 0.f;
    w1sw[t] = f2h(v);
  } else if (t < 147456 + 32768) {
    int t2 = t - 147456;
    int chunk = t2 >> 13, rem = t2 & 8191;
    int kq = rem >> 10, n = (rem >> 3) & 127, j = rem & 7;
    int k = (chunk << 6) + (kq << 3) + j;          // < 256 always
    w2sw[t2] = f2h(W2[k * 128 + n]);
  } else if (t < 147456 + 32768 + 2048) {
    int t3 = t - 180224;
    int kq = t3 >> 7, o = (t3 >> 3) & 15, j = t3 & 7;
    int k = (kq << 3) + j;                          // < 128
    w3sw[t3] = f2h((o < 5) ? W3[k * 5 + o] : 0.f);
  }
}

// ---- fused main kernel: 64 edges per block, 256 threads (4 waves) ----
// All GEMMs computed transposed: z1^T = W1^T (A) * feats^T (B), etc.
// A-frag: A[m=lane&15][k=(lane>>4)*8+j];  B-frag: B[k=(lane>>4)*8+j][n=lane&15]
// D: row m=(lane>>4)*4+reg (channel dim), col n=lane&15 (edge dim)
struct __align__(16) SMem {
  short r1[16896];    // 33792B: A1 chunk (16384 el) / z1T [64][264]
  short r2[8704];     // 17408B: feats [64][72] / A2 chunk (8192 el) / z2T [64][136]
  short w3s[2048];    // 4096B : W3 swizzled (A-frag layout), persistent
  float b1v[256], g1v[256], be1v[256];
  float b2v[128], g2v[128], be2v[128];
  float muv[16];
  float b3v[8];
  float redS[4][64], redQ[4][64];
  int spI[64], exI[64];
};

__global__ __launch_bounds__(256, 2)
void edge_head_main(const float* __restrict__ h, const float* __restrict__ x,
                    const int* __restrict__ spawn, const int* __restrict__ exist,
                    const float* __restrict__ insx, const int* __restrict__ insa,
                    const int* __restrict__ insc,
                    const float* __restrict__ b1, const float* __restrict__ g1,
                    const float* __restrict__ be1,
                    const float* __restrict__ b2, const float* __restrict__ g2,
                    const float* __restrict__ be2,
                    const float* __restrict__ b3, const float* __restrict__ mu,
                    const float* __restrict__ gammaP,
                    const unsigned short* __restrict__ w1sw,
                    const unsigned short* __restrict__ w2sw,
                    const unsigned short* __restrict__ w3swg,
                    const unsigned short* __restrict__ hb, int use_hb,
                    float* __restrict__ out) {
  __shared__ SMem sm;
  const int t = threadIdx.x;
  const int base = blockIdx.x * 64;
  const int lane = t & 63;
  const int wv = t >> 6;
  const int cl = lane & 15;
  const int q = lane >> 4;

  // ---- const staging ----
  sm.b1v[t] = b1[t]; sm.g1v[t] = g1[t]; sm.be1v[t] = be1[t];
  if (t < 128) { sm.b2v[t] = b2[t]; sm.g2v[t] = g2[t]; sm.be2v[t] = be2[t]; }
  if (t < 16) sm.muv[t] = mu[t];
  if (t < 8) sm.b3v[t] = (t < 5) ? b3[t] : 0.f;
  if (t < 64) {
    int e = base + t; int ec = e < EE ? e : EE - 1;
    sm.spI[t] = spawn[ec]; sm.exI[t] = exist[ec];
  }
  *(int4*)&sm.w3s[t * 8] = *(const int4*)&w3swg[t * 8];
  const float gma = gammaP[0];

  // ---- GEMM1: z1^T[256][64] = W1^T * feats^T, K = 576 in 9 chunks of 64 ----
  f32x4 acc[4][4];
#pragma unroll
  for (int i = 0; i < 4; ++i)
#pragma unroll
    for (int j = 0; j < 4; ++j) acc[i][j] = (f32x4){0.f, 0.f, 0.f, 0.f};

  for (int c = 0; c < 9; ++c) {
    __syncthreads();
    // stage A1 chunk: 32KB contiguous, async direct-to-LDS
    const unsigned short* gsrc = w1sw + c * 16384;
#pragma unroll
    for (int i = 0; i < 8; ++i)
      g2l16(&sm.r1[(i * 256 + t) * 8], gsrc + (i * 256 + t) * 8);
    // stage B (feats^T chunk): gathered h rows, [64][72] fp16 (pad keeps 16B align, 2-way banks)
    if (c < 8) {
      const int* sel = (c < 4) ? sm.spI : sm.exI;
      const int colb = (c & 3) * 64;
#pragma unroll
      for (int i = 0; i < 2; ++i) {
        int jj = t + i * 256;
        int row = jj >> 3, p = jj & 7;
        int node = sel[row];
        if (use_hb) {
          *(int4*)&sm.r2[row * 72 + p * 8] = *(const int4*)(hb + node * HIDD + colb + p * 8);
        } else {
          const float* s = h + node * HIDD + colb + p * 8;
          float4 v0 = *(const float4*)s, v1 = *(const float4*)(s + 4);
          union { unsigned short us[8]; int4 v; } u;
          u.us[0] = f2h(v0.x); u.us[1] = f2h(v0.y); u.us[2] = f2h(v0.z); u.us[3] = f2h(v0.w);
          u.us[4] = f2h(v1.x); u.us[5] = f2h(v1.y); u.us[6] = f2h(v1.z); u.us[7] = f2h(v1.w);
          *(int4*)&sm.r2[row * 72 + p * 8] = u.v;
        }
      }
    } else {
      // chunk 8 = built features: [rbf(16) | atom onehot(16) | charge onehot(7) | 0...]
      if (t < 64) {
        int e = base + t; int ec = e < EE ? e : EE - 1;
        float ix0 = insx[ec * 3], ix1 = insx[ec * 3 + 1], ix2 = insx[ec * 3 + 2];
        int nd = sm.exI[t];
        float dx = ix0 - x[nd * 3], dy = ix1 - x[nd * 3 + 1], dz = ix2 - x[nd * 3 + 2];
        float d = fmaxf(sqrtf(dx * dx + dy * dy + dz * dz), 1e-6f);
        int a = insa[ec], cg = insc[ec];
        short* rp = &sm.r2[t * 72];
#pragma unroll
        for (int k = 0; k < 16; ++k) {
          float dd = d - sm.muv[k];
          rp[k] = (short)f2h(__expf(-gma * dd * dd));
        }
#pragma unroll
        for (int k = 16; k < 64; ++k) rp[k] = 0;
        rp[16 + a] = (short)0x3C00;   // fp16 1.0
        rp[32 + cg] = (short)0x3C00;
      }
    }
    __syncthreads();
#pragma unroll
    for (int ks = 0; ks < 2; ++ks) {
      half8 af[4], bf[4];
#pragma unroll
      for (int i = 0; i < 4; ++i)
        af[i] = *(const half8*)&sm.r1[(ks * 4 + q) * 2048 + (wv * 64 + i * 16 + cl) * 8];
#pragma unroll
      for (int j = 0; j < 4; ++j)
        bf[j] = *(const half8*)&sm.r2[(j * 16 + cl) * 72 + ks * 32 + q * 8];
#pragma unroll
      for (int i = 0; i < 4; ++i)
#pragma unroll
        for (int j = 0; j < 4; ++j)
          acc[i][j] = __builtin_amdgcn_mfma_f32_16x16x32_f16(af[i], bf[j], acc[i][j], 0, 0, 0);
    }
  }

  // ---- +b1, LayerNorm over 256 channels (per edge), SiLU, pack to z1T ----
#pragma unroll
  for (int i = 0; i < 4; ++i) {
    float bb[4];
#pragma unroll
    for (int r = 0; r < 4; ++r) bb[r] = sm.b1v[wv * 64 + i * 16 + q * 4 + r];
#pragma unroll
    for (int j = 0; j < 4; ++j)
#pragma unroll
      for (int r = 0; r < 4; ++r) acc[i][j][r] += bb[r];
  }
#pragma unroll
  for (int j = 0; j < 4; ++j) {
    float S = 0.f, Q = 0.f;
#pragma unroll
    for (int i = 0; i < 4; ++i)
#pragma unroll
      for (int r = 0; r < 4; ++r) { float v = acc[i][j][r]; S += v; Q += v * v; }
    S += __shfl_xor(S, 16); S += __shfl_xor(S, 32);
    Q += __shfl_xor(Q, 16); Q += __shfl_xor(Q, 32);
    if (q == 0) { sm.redS[wv][j * 16 + cl] = S; sm.redQ[wv][j * 16 + cl] = Q; }
  }
  __syncthreads();   // also guarantees all waves finished reading A1 before z1T overwrite
  float mean1[4], rstd1[4];
#pragma unroll
  for (int j = 0; j < 4; ++j) {
    int m = j * 16 + cl;
    float S = sm.redS[0][m] + sm.redS[1][m] + sm.redS[2][m] + sm.redS[3][m];
    float Q = sm.redQ[0][m] + sm.redQ[1][m] + sm.redQ[2][m] + sm.redQ[3][m];
    float mn = S * (1.f / 256.f);
    mean1[j] = mn;
    rstd1[j] = rsqrtf(Q * (1.f / 256.f) - mn * mn + LN_EPS);
  }
#pragma unroll
  for (int i = 0; i < 4; ++i)
#pragma unroll
    for (int j = 0; j < 4; ++j) {
      unsigned short us[4];
#pragma unroll
      for (int r = 0; r < 4; ++r) {
        int n = wv * 64 + i * 16 + q * 4 + r;
        float y = (acc[i][j][r] - mean1[j]) * rstd1[j] * sm.g1v[n] + sm.be1v[n];
        float s = y / (1.f + __expf(-y));
        us[r] = f2h(s);
      }
      uint2 w;
      w.x = (unsigned)us[0] | ((unsigned)us[1] << 16);
      w.y = (unsigned)us[2] | ((unsigned)us[3] << 16);
      int m = j * 16 + cl;
      *(uint2*)&sm.r1[m * 264 + wv * 64 + i * 16 + q * 4] = w;   // z1T[edge][264]
    }

  // ---- GEMM2: z2^T[128][64] = W2^T * z1^T, K = 256 in 4 chunks of 64 ----
  f32x4 acc2[2][4];
#pragma unroll
  for (int i = 0; i < 2; ++i)
#pragma unroll
    for (int j = 0; j < 4; ++j) acc2[i][j] = (f32x4){0.f, 0.f, 0.f, 0.f};
  for (int c2 = 0; c2 < 4; ++c2) {
    __syncthreads();   // first iter: z1T writes visible; feats region dead
    const unsigned short* gsrc = w2sw + c2 * 8192;
#pragma unroll
    for (int i = 0; i < 4; ++i)
      g2l16(&sm.r2[(i * 256 + t) * 8], gsrc + (i * 256 + t) * 8);
    __syncthreads();
#pragma unroll
    for (int ks = 0; ks < 2; ++ks) {
      half8 af[2], bf[4];
#pragma unroll
      for (int i = 0; i < 2; ++i)
        af[i] = *(const half8*)&sm.r2[(ks * 4 + q) * 1024 + (wv * 32 + i * 16 + cl) * 8];
#pragma unroll
      for (int j = 0; j < 4; ++j)
        bf[j] = *(const half8*)&sm.r1[(j * 16 + cl) * 264 + c2 * 64 + ks * 32 + q * 8];
#pragma unroll
      for (int i = 0; i < 2; ++i)
#pragma unroll
        for (int j = 0; j < 4; ++j)
          acc2[i][j] = __builtin_amdgcn_mfma_f32_16x16x32_f16(af[i], bf[j], acc2[i][j], 0, 0, 0);
    }
  }

  // ---- +b2, LN over 128, SiLU, pack z2T into r2 ----
#pragma unroll
  for (int i = 0; i < 2; ++i) {
    float bb[4];
#pragma unroll
    for (int r = 0; r < 4; ++r) bb[r] = sm.b2v[wv * 32 + i * 16 + q * 4 + r];
#pragma unroll
    for (int j = 0; j < 4; ++j)
#pragma unroll
      for (int r = 0; r < 4; ++r) acc2[i][j][r] += bb[r];
  }
#pragma unroll
  for (int j = 0; j < 4; ++j) {
    float S = 0.f, Q = 0.f;
#pragma unroll
    for (int i = 0; i < 2; ++i)
#pragma unroll
      for (int r = 0; r < 4; ++r) { float v = acc2[i][j][r]; S += v; Q += v * v; }
    S += __shfl_xor(S, 16); S += __shfl_xor(S, 32);
    Q += __shfl_xor(Q, 16); Q += __shfl_xor(Q, 32);
    if (q == 0) { sm.redS[wv][j * 16 + cl] = S; sm.redQ[wv][j * 16 + cl] = Q; }
  }
  __syncthreads();   // all waves past GEMM2 mfma -> safe to overwrite A2 region with z2T
  float mean2[4], rstd2[4];
#pragma unroll
  for (int j = 0; j < 4; ++j) {
    int m = j * 16 + cl;
    float S = sm.redS[0][m] + sm.redS[1][m] + sm.redS[2][m] + sm.redS[3][m];
    float Q = sm.redQ[0][m] + sm.redQ[1][m] + sm.redQ[2][m] + sm.redQ[3][m];
    float mn = S * (1.f / 128.f);
    mean2[j] = mn;
    rstd2[j] = rsqrtf(Q * (1.f / 128.f) - mn * mn + LN_EPS);
  }
#pragma unroll
  for (int i = 0; i < 2; ++i)
#pragma unroll
    for (int j = 0; j < 4; ++j) {
      unsigned short us[4];
#pragma unroll
      for (int r = 0; r < 4; ++r) {
        int n = wv * 32 + i * 16 + q * 4 + r;
        float y = (acc2[i][j][r] - mean2[j]) * rstd2[j] * sm.g2v[n] + sm.be2v[n];
        float s = y / (1.f + __expf(-y));
        us[r] = f2h(s);
      }
      uint2 w;
      w.x = (unsigned)us[0] | ((unsigned)us[1] << 16);
      w.y = (unsigned)us[2] | ((unsigned)us[3] << 16);
      int m = j * 16 + cl;
      *(uint2*)&sm.r2[m * 136 + wv * 32 + i * 16 + q * 4] = w;   // z2T[edge][136]
    }
  __syncthreads();

  // ---- GEMM3: out^T[16][64] = W3^T * z2^T (o padded 5->16), wave wv owns edges wv*16.. ----
  f32x4 a3 = (f32x4){0.f, 0.f, 0.f, 0.f};
#pragma unroll
  for (int ks = 0; ks < 4; ++ks) {
    half8 af = *(const half8*)&sm.w3s[(ks * 4 + q) * 128 + cl * 8];
    half8 bf = *(const half8*)&sm.r2[(wv * 16 + cl) * 136 + ks * 32 + q * 8];
    a3 = __builtin_amdgcn_mfma_f32_16x16x32_f16(af, bf, a3, 0, 0, 0);
  }
  int e = base + wv * 16 + cl;
  if (e < EE) {
#pragma unroll
    for (int r = 0; r < 4; ++r) {
      int o = q * 4 + r;
      if (o < 5) out[e * 5 + o] = a3[r] + sm.b3v[o];
    }
  }
}

extern "C" void kernel_launch(void* const* d_in, const int* in_sizes, int n_in,
                              void* d_out, int out_size, void* d_ws, size_t ws_size,
                              hipStream_t stream) {
  const float* h    = (const float*)d_in[0];
  const float* x    = (const float*)d_in[1];
  const int* spawn  = (const int*)d_in[2];
  const int* exist  = (const int*)d_in[3];
  const float* insx = (const float*)d_in[4];
  const int* insa   = (const int*)d_in[5];
  const int* insc   = (const int*)d_in[6];
  const float* W1   = (const float*)d_in[7];
  const float* b1   = (const float*)d_in[8];
  const float* g1   = (const float*)d_in[9];
  const float* be1  = (const float*)d_in[10];
  const float* W2   = (const float*)d_in[11];
  const float* b2   = (const float*)d_in[12];
  const float* g2   = (const float*)d_in[13];
  const float* be2  = (const float*)d_in[14];
  const float* W3   = (const float*)d_in[15];
  const float* b3   = (const float*)d_in[16];
  const float* mu   = (const float*)d_in[17];
  const float* gma  = (const float*)d_in[18];

  unsigned short* w1sw = (unsigned short*)d_ws;          // 147456 el
  unsigned short* w2sw = w1sw + 147456;                  // 32768 el
  unsigned short* w3sw = w2sw + 32768;                   // 2048 el
  unsigned short* hb   = w3sw + 2048;                    // N*HID el (optional)
  const size_t need_hb = 364544ull + (size_t)NN * HIDD * 2ull;
  int use_hb = (ws_size >= need_hb) ? 1 : 0;

  conv_w_kern<<<712, 256, 0, stream>>>(W1, W2, W3, w1sw, w2sw, w3sw);
  if (use_hb) conv_h_kern<<<12500, 256, 0, stream>>>(h, hb);
  edge_head_main<<<7813, 256, 0, stream>>>(h, x, spawn, exist, insx, insa, insc,
                                           b1, g1, be1, b2, g2, be2, b3, mu, gma,
                                           w1sw, w2sw, w3sw, hb, use_hb,
                                           (float*)d_out);
}

// Round 4
// 540.193 us; speedup vs baseline: 1.0976x; 1.0976x over previous
//
#include <hip/hip_runtime.h>
#include <stdint.h>

#define NN 100000      // nodes
#define EE 500000      // edges
#define HIDD 256
#define LN_EPS 1e-5f

typedef _Float16 half8 __attribute__((ext_vector_type(8)));  // 8 fp16 (4 VGPRs)
typedef _Float16 half4 __attribute__((ext_vector_type(4)));
typedef float f32x4 __attribute__((ext_vector_type(4)));

__device__ __forceinline__ unsigned short f2h(float f) {
  _Float16 h = (_Float16)f;                 // v_cvt_f16_f32, RNE
  union { _Float16 hh; unsigned short us; } u; u.hh = h;
  return u.us;
}

__device__ __forceinline__ void g2l16(void* lds, const void* g) {
  __builtin_amdgcn_global_load_lds(
      (const __attribute__((address_space(1))) unsigned int*)g,
      (__attribute__((address_space(3))) unsigned int*)lds, 16, 0, 0);
}

// ---- merged prep: weight swizzle (blocks 0..711) + h f32->fp16 (blocks 712..13211) ----
// W1T_sw: [chunk k/64][kq (k%64)/8][n 0..255][j k%8], k>=551 zero.  147456 elems
// W2T_sw: [chunk][kq][n2 0..127][j]                                  32768 elems
// W3_sw : [kq k/8][o 0..15][j], o>=5 zero                            2048 elems
__global__ __launch_bounds__(256) void prep_kern(const float* __restrict__ h,
                                                 const float* __restrict__ W1,
                                                 const float* __restrict__ W2,
                                                 const float* __restrict__ W3,
                                                 unsigned short* __restrict__ hb,
                                                 unsigned short* __restrict__ w1sw,
                                                 unsigned short* __restrict__ w2sw,
                                                 unsigned short* __restrict__ w3sw) {
  int b = blockIdx.x;
  if (b < 712) {
    int t = b * 256 + threadIdx.x;
    if (t < 147456) {
      int chunk = t >> 14, rem = t & 16383;
      int kq = rem >> 11, n = (rem >> 3) & 255, j = rem & 7;
      int k = (chunk << 6) + (kq << 3) + j;
      float v = (k < 551) ? W1[k * 256 + n] : 0.f;
      w1sw[t] = f2h(v);
    } else if (t < 147456 + 32768) {
      int t2 = t - 147456;
      int chunk = t2 >> 13, rem = t2 & 8191;
      int kq = rem >> 10, n = (rem >> 3) & 127, j = rem & 7;
      int k = (chunk << 6) + (kq << 3) + j;
      w2sw[t2] = f2h(W2[k * 128 + n]);
    } else if (t < 147456 + 32768 + 2048) {
      int t3 = t - 180224;
      int kq = t3 >> 7, o = (t3 >> 3) & 15, j = t3 & 7;
      int k = (kq << 3) + j;
      w3sw[t3] = f2h((o < 5) ? W3[k * 5 + o] : 0.f);
    }
  } else {
    int i = ((b - 712) * 256 + threadIdx.x) * 8;   // N*HID = 25.6M = 12500*256*8
    float4 v0 = *(const float4*)(h + i);
    float4 v1 = *(const float4*)(h + i + 4);
    union { unsigned short us[8]; int4 v; } u;
    u.us[0] = f2h(v0.x); u.us[1] = f2h(v0.y); u.us[2] = f2h(v0.z); u.us[3] = f2h(v0.w);
    u.us[4] = f2h(v1.x); u.us[5] = f2h(v1.y); u.us[6] = f2h(v1.z); u.us[7] = f2h(v1.w);
    *(int4*)(hb + i) = u.v;
  }
}

// ---- fused main kernel: 64 edges per block, 256 threads (4 waves), 3 blocks/CU ----
// All GEMMs transposed: z1^T = W1^T (A) * feats^T (B), etc.
// A-frag: A[m=lane&15][k=(lane>>4)*8+j];  B-frag: B[k=(lane>>4)*8+j][n=lane&15]
// D: row m=(lane>>4)*4+reg (channel), col n=lane&15 (edge)
// z1T/z2T/feats use XOR swizzle: elem(row,k) at row*S + (k ^ ((row&7)<<3)) — pure
// permutation within 8-half groups, keeps ds b64/b128 alignment, frees the +8 pad.
struct __align__(16) SMem {
  short r1[16384];    // 32768B: A1 chunk / z1T [64][256]swz / w3s at +2048el after GEMM2
  short r2[8192];     // 16384B: feats [64][64]swz / A2 chunk (8192 el) / z2T [64][128]swz
  _Float16 b1h[256], g1h[256], be1h[256];   // 1536B
  _Float16 b2h[128], g2h[128], be2h[128];   // 768B
  float muv[16];      // 64B
  float b3v[8];       // 32B
  float redS[4][64], redQ[4][64];           // 2048B
  int spI[64], exI[64];                     // 512B
};  // 54112 B -> 3 blocks/CU (160K/54.1K)

__global__ __launch_bounds__(256, 3)
void edge_head_main(const float* __restrict__ h, const float* __restrict__ x,
                    const int* __restrict__ spawn, const int* __restrict__ exist,
                    const float* __restrict__ insx, const int* __restrict__ insa,
                    const int* __restrict__ insc,
                    const float* __restrict__ b1, const float* __restrict__ g1,
                    const float* __restrict__ be1,
                    const float* __restrict__ b2, const float* __restrict__ g2,
                    const float* __restrict__ be2,
                    const float* __restrict__ b3, const float* __restrict__ mu,
                    const float* __restrict__ gammaP,
                    const unsigned short* __restrict__ w1sw,
                    const unsigned short* __restrict__ w2sw,
                    const unsigned short* __restrict__ w3swg,
                    const unsigned short* __restrict__ hb, int use_hb,
                    float* __restrict__ out) {
  __shared__ SMem sm;
  const int t = threadIdx.x;
  const int base = blockIdx.x * 64;
  const int lane = t & 63;
  const int wv = t >> 6;
  const int cl = lane & 15;
  const int q = lane >> 4;
  const int sx = (cl & 7) << 3;   // B-frag read swizzle term (erow&7 == cl&7)

  // ---- const staging ----
  sm.b1h[t] = (_Float16)b1[t]; sm.g1h[t] = (_Float16)g1[t]; sm.be1h[t] = (_Float16)be1[t];
  if (t < 128) { sm.b2h[t] = (_Float16)b2[t]; sm.g2h[t] = (_Float16)g2[t]; sm.be2h[t] = (_Float16)be2[t]; }
  if (t < 16) sm.muv[t] = mu[t];
  if (t < 8) sm.b3v[t] = (t < 5) ? b3[t] : 0.f;
  if (t < 64) {
    int e = base + t; int ec = e < EE ? e : EE - 1;
    sm.spI[t] = spawn[ec]; sm.exI[t] = exist[ec];
  }
  const float gma = gammaP[0];

  __syncthreads();   // spI/exI visible for prefetch

  // gather slots: this thread fills feats rows row0 (piece p0) and row1
  const int row0 = t >> 3, p0 = t & 7;
  const int row1 = row0 + 32;
  const int sw0 = ((p0 ^ (row0 & 7)) << 3);   // swizzled k-offset for 16B piece
  const int sw1 = ((p0 ^ (row1 & 7)) << 3);

  int4 pA, pB;
  if (use_hb) {   // prefetch chunk 0 (spawn, colb=0)
    pA = *(const int4*)(hb + (size_t)sm.spI[row0] * HIDD + p0 * 8);
    pB = *(const int4*)(hb + (size_t)sm.spI[row1] * HIDD + p0 * 8);
  }

  // ---- GEMM1: z1^T[256][64] = W1^T * feats^T, K = 576 in 9 chunks of 64 ----
  f32x4 acc[4][4];
#pragma unroll
  for (int i = 0; i < 4; ++i)
#pragma unroll
    for (int j = 0; j < 4; ++j) acc[i][j] = (f32x4){0.f, 0.f, 0.f, 0.f};

  for (int c = 0; c < 9; ++c) {
    __syncthreads();   // prev MFMAs done -> A1/feats regions reusable
    const unsigned short* gsrc = w1sw + c * 16384;
#pragma unroll
    for (int i = 0; i < 8; ++i)
      g2l16(&sm.r1[(i * 256 + t) * 8], gsrc + (i * 256 + t) * 8);
    if (c < 8) {
      if (use_hb) {
        *(int4*)&sm.r2[row0 * 64 + sw0] = pA;   // regs from prev-iteration issue
        *(int4*)&sm.r2[row1 * 64 + sw1] = pB;
        if (c < 7) {   // prefetch next chunk's gather
          const int cn = c + 1;
          const int* sel = (cn < 4) ? sm.spI : sm.exI;
          const int colb = (cn & 3) * 64;
          pA = *(const int4*)(hb + (size_t)sel[row0] * HIDD + colb + p0 * 8);
          pB = *(const int4*)(hb + (size_t)sel[row1] * HIDD + colb + p0 * 8);
        }
      } else {
        const int* sel = (c < 4) ? sm.spI : sm.exI;
        const int colb = (c & 3) * 64;
#pragma unroll
        for (int i = 0; i < 2; ++i) {
          int jj = t + i * 256;
          int row = jj >> 3, p = jj & 7;
          const float* s = h + (size_t)sel[row] * HIDD + colb + p * 8;
          float4 v0 = *(const float4*)s, v1 = *(const float4*)(s + 4);
          union { unsigned short us[8]; int4 v; } u;
          u.us[0] = f2h(v0.x); u.us[1] = f2h(v0.y); u.us[2] = f2h(v0.z); u.us[3] = f2h(v0.w);
          u.us[4] = f2h(v1.x); u.us[5] = f2h(v1.y); u.us[6] = f2h(v1.z); u.us[7] = f2h(v1.w);
          *(int4*)&sm.r2[row * 64 + ((p ^ (row & 7)) << 3)] = u.v;
        }
      }
    } else {
      // chunk 8 = built features: [rbf(16) | atom onehot(16) | charge onehot(7) | 0..]
      if (t < 64) {
        int e = base + t; int ec = e < EE ? e : EE - 1;
        float ix0 = insx[ec * 3], ix1 = insx[ec * 3 + 1], ix2 = insx[ec * 3 + 2];
        int nd = sm.exI[t];
        float dx = ix0 - x[nd * 3], dy = ix1 - x[nd * 3 + 1], dz = ix2 - x[nd * 3 + 2];
        float d = fmaxf(sqrtf(dx * dx + dy * dy + dz * dz), 1e-6f);
        int a = insa[ec], cg = insc[ec];
        short* rp = &sm.r2[t * 64];
        int s = (t & 7) << 3;
#pragma unroll
        for (int k = 0; k < 64; ++k) rp[k] = 0;   // XOR is a within-row permutation
#pragma unroll
        for (int k = 0; k < 16; ++k) {
          float dd = d - sm.muv[k];
          rp[k ^ s] = (short)f2h(__expf(-gma * dd * dd));
        }
        rp[(16 + a) ^ s] = (short)0x3C00;   // fp16 1.0
        rp[(32 + cg) ^ s] = (short)0x3C00;
      }
    }
    __syncthreads();
#pragma unroll
    for (int ks = 0; ks < 2; ++ks) {
      half8 af[4], bf[4];
#pragma unroll
      for (int i = 0; i < 4; ++i)
        af[i] = *(const half8*)&sm.r1[(ks * 4 + q) * 2048 + (wv * 64 + i * 16 + cl) * 8];
#pragma unroll
      for (int j = 0; j < 4; ++j)
        bf[j] = *(const half8*)&sm.r2[(j * 16 + cl) * 64 + ((ks * 32 + q * 8) ^ sx)];
#pragma unroll
      for (int i = 0; i < 4; ++i)
#pragma unroll
        for (int j = 0; j < 4; ++j)
          acc[i][j] = __builtin_amdgcn_mfma_f32_16x16x32_f16(af[i], bf[j], acc[i][j], 0, 0, 0);
    }
  }

  // ---- +b1, LayerNorm over 256 channels (per edge), SiLU, pack to z1T ----
#pragma unroll
  for (int i = 0; i < 4; ++i) {
    half4 bb = *(const half4*)&sm.b1h[wv * 64 + i * 16 + q * 4];
#pragma unroll
    for (int j = 0; j < 4; ++j)
#pragma unroll
      for (int r = 0; r < 4; ++r) acc[i][j][r] += (float)bb[r];
  }
#pragma unroll
  for (int j = 0; j < 4; ++j) {
    float S = 0.f, Q = 0.f;
#pragma unroll
    for (int i = 0; i < 4; ++i)
#pragma unroll
      for (int r = 0; r < 4; ++r) { float v = acc[i][j][r]; S += v; Q += v * v; }
    S += __shfl_xor(S, 16); S += __shfl_xor(S, 32);
    Q += __shfl_xor(Q, 16); Q += __shfl_xor(Q, 32);
    if (q == 0) { sm.redS[wv][j * 16 + cl] = S; sm.redQ[wv][j * 16 + cl] = Q; }
  }
  __syncthreads();   // redS visible; all waves past A1 reads -> z1T overwrite safe
  float mean1[4], rstd1[4];
#pragma unroll
  for (int j = 0; j < 4; ++j) {
    int m = j * 16 + cl;
    float S = sm.redS[0][m] + sm.redS[1][m] + sm.redS[2][m] + sm.redS[3][m];
    float Q = sm.redQ[0][m] + sm.redQ[1][m] + sm.redQ[2][m] + sm.redQ[3][m];
    float mn = S * (1.f / 256.f);
    mean1[j] = mn;
    rstd1[j] = rsqrtf(Q * (1.f / 256.f) - mn * mn + LN_EPS);
  }
#pragma unroll
  for (int i = 0; i < 4; ++i) {
    half4 g4 = *(const half4*)&sm.g1h[wv * 64 + i * 16 + q * 4];
    half4 e4 = *(const half4*)&sm.be1h[wv * 64 + i * 16 + q * 4];
#pragma unroll
    for (int j = 0; j < 4; ++j) {
      unsigned short us[4];
#pragma unroll
      for (int r = 0; r < 4; ++r) {
        float y = (acc[i][j][r] - mean1[j]) * rstd1[j] * (float)g4[r] + (float)e4[r];
        float s = y / (1.f + __expf(-y));
        us[r] = f2h(s);
      }
      uint2 w;
      w.x = (unsigned)us[0] | ((unsigned)us[1] << 16);
      w.y = (unsigned)us[2] | ((unsigned)us[3] << 16);
      int m = j * 16 + cl;
      int k0 = wv * 64 + i * 16 + q * 4;
      *(uint2*)&sm.r1[m * 256 + (k0 ^ ((m & 7) << 3))] = w;   // z1T swizzled
    }
  }

  // ---- GEMM2: z2^T[128][64] = W2^T * z1^T, K = 256 in 4 chunks of 64 ----
  f32x4 acc2[2][4];
#pragma unroll
  for (int i = 0; i < 2; ++i)
#pragma unroll
    for (int j = 0; j < 4; ++j) acc2[i][j] = (f32x4){0.f, 0.f, 0.f, 0.f};
  for (int c2 = 0; c2 < 4; ++c2) {
    __syncthreads();   // z1T writes visible (first) / prev A2 reads done
    const unsigned short* gsrc = w2sw + c2 * 8192;
#pragma unroll
    for (int i = 0; i < 4; ++i)
      g2l16(&sm.r2[(i * 256 + t) * 8], gsrc + (i * 256 + t) * 8);
    __syncthreads();
#pragma unroll
    for (int ks = 0; ks < 2; ++ks) {
      half8 af[2], bf[4];
#pragma unroll
      for (int i = 0; i < 2; ++i)
        af[i] = *(const half8*)&sm.r2[(ks * 4 + q) * 1024 + (wv * 32 + i * 16 + cl) * 8];
#pragma unroll
      for (int j = 0; j < 4; ++j)
        bf[j] = *(const half8*)&sm.r1[(j * 16 + cl) * 256 + ((c2 * 64 + ks * 32 + q * 8) ^ sx)];
#pragma unroll
      for (int i = 0; i < 2; ++i)
#pragma unroll
        for (int j = 0; j < 4; ++j)
          acc2[i][j] = __builtin_amdgcn_mfma_f32_16x16x32_f16(af[i], bf[j], acc2[i][j], 0, 0, 0);
    }
  }
  __syncthreads();   // all waves past GEMM2 (z1T/A2 reads done) -> r1 reusable for w3s

  // stage W3 fragments into dead z1T space (r1 + 2048 el), async
  g2l16(&sm.r1[2048 + t * 8], w3swg + t * 8);

  // ---- +b2, LN over 128, SiLU, pack z2T into r2 ----
#pragma unroll
  for (int i = 0; i < 2; ++i) {
    half4 bb = *(const half4*)&sm.b2h[wv * 32 + i * 16 + q * 4];
#pragma unroll
    for (int j = 0; j < 4; ++j)
#pragma unroll
      for (int r = 0; r < 4; ++r) acc2[i][j][r] += (float)bb[r];
  }
#pragma unroll
  for (int j = 0; j < 4; ++j) {
    float S = 0.f, Q = 0.f;
#pragma unroll
    for (int i = 0; i < 2; ++i)
#pragma unroll
      for (int r = 0; r < 4; ++r) { float v = acc2[i][j][r]; S += v; Q += v * v; }
    S += __shfl_xor(S, 16); S += __shfl_xor(S, 32);
    Q += __shfl_xor(Q, 16); Q += __shfl_xor(Q, 32);
    if (q == 0) { sm.redS[wv][j * 16 + cl] = S; sm.redQ[wv][j * 16 + cl] = Q; }
  }
  __syncthreads();   // redS visible (w3s DMA also drained by barrier semantics)
  float mean2[4], rstd2[4];
#pragma unroll
  for (int j = 0; j < 4; ++j) {
    int m = j * 16 + cl;
    float S = sm.redS[0][m] + sm.redS[1][m] + sm.redS[2][m] + sm.redS[3][m];
    float Q = sm.redQ[0][m] + sm.redQ[1][m] + sm.redQ[2][m] + sm.redQ[3][m];
    float mn = S * (1.f / 128.f);
    mean2[j] = mn;
    rstd2[j] = rsqrtf(Q * (1.f / 128.f) - mn * mn + LN_EPS);
  }
#pragma unroll
  for (int i = 0; i < 2; ++i) {
    half4 g4 = *(const half4*)&sm.g2h[wv * 32 + i * 16 + q * 4];
    half4 e4 = *(const half4*)&sm.be2h[wv * 32 + i * 16 + q * 4];
#pragma unroll
    for (int j = 0; j < 4; ++j) {
      unsigned short us[4];
#pragma unroll
      for (int r = 0; r < 4; ++r) {
        float y = (acc2[i][j][r] - mean2[j]) * rstd2[j] * (float)g4[r] + (float)e4[r];
        float s = y / (1.f + __expf(-y));
        us[r] = f2h(s);
      }
      uint2 w;
      w.x = (unsigned)us[0] | ((unsigned)us[1] << 16);
      w.y = (unsigned)us[2] | ((unsigned)us[3] << 16);
      int m = j * 16 + cl;
      int k0 = wv * 32 + i * 16 + q * 4;
      *(uint2*)&sm.r2[m * 128 + (k0 ^ ((m & 7) << 3))] = w;   // z2T swizzled
    }
  }
  __syncthreads();   // z2T + w3s visible

  // ---- GEMM3: out^T[16][64] = W3^T * z2^T (o padded 5->16), wave wv owns edges wv*16.. ----
  f32x4 a3 = (f32x4){0.f, 0.f, 0.f, 0.f};
  const int m3 = wv * 16 + cl;
  const int sx3 = (m3 & 7) << 3;
#pragma unroll
  for (int ks = 0; ks < 4; ++ks) {
    half8 af = *(const half8*)&sm.r1[2048 + (ks * 4 + q) * 128 + cl * 8];
    half8 bf = *(const half8*)&sm.r2[m3 * 128 + ((ks * 32 + q * 8) ^ sx3)];
    a3 = __builtin_amdgcn_mfma_f32_16x16x32_f16(af, bf, a3, 0, 0, 0);
  }
  int e = base + m3;
  if (e < EE) {
#pragma unroll
    for (int r = 0; r < 4; ++r) {
      int o = q * 4 + r;
      if (o < 5) out[e * 5 + o] = a3[r] + sm.b3v[o];
    }
  }
}

extern "C" void kernel_launch(void* const* d_in, const int* in_sizes, int n_in,
                              void* d_out, int out_size, void* d_ws, size_t ws_size,
                              hipStream_t stream) {
  const float* h    = (const float*)d_in[0];
  const float* x    = (const float*)d_in[1];
  const int* spawn  = (const int*)d_in[2];
  const int* exist  = (const int*)d_in[3];
  const float* insx = (const float*)d_in[4];
  const int* insa   = (const int*)d_in[5];
  const int* insc   = (const int*)d_in[6];
  const float* W1   = (const float*)d_in[7];
  const float* b1   = (const float*)d_in[8];
  const float* g1   = (const float*)d_in[9];
  const float* be1  = (const float*)d_in[10];
  const float* W2   = (const float*)d_in[11];
  const float* b2   = (const float*)d_in[12];
  const float* g2   = (const float*)d_in[13];
  const float* be2  = (const float*)d_in[14];
  const float* W3   = (const float*)d_in[15];
  const float* b3   = (const float*)d_in[16];
  const float* mu   = (const float*)d_in[17];
  const float* gma  = (const float*)d_in[18];

  unsigned short* w1sw = (unsigned short*)d_ws;          // 147456 el
  unsigned short* w2sw = w1sw + 147456;                  // 32768 el
  unsigned short* w3sw = w2sw + 32768;                   // 2048 el
  unsigned short* hb   = w3sw + 2048;                    // N*HID el (optional)
  const size_t need_hb = 364544ull + (size_t)NN * HIDD * 2ull;
  int use_hb = (ws_size >= need_hb) ? 1 : 0;

  prep_kern<<<use_hb ? 13212 : 712, 256, 0, stream>>>(h, W1, W2, W3, hb, w1sw, w2sw, w3sw);
  edge_head_main<<<7813, 256, 0, stream>>>(h, x, spawn, exist, insx, insa, insc,
                                           b1, g1, be1, b2, g2, be2, b3, mu, gma,
                                           w1sw, w2sw, w3sw, hb, use_hb,
                                           (float*)d_out);
}

// Round 6
// 463.237 us; speedup vs baseline: 1.2799x; 1.1661x over previous
//
#include <hip/hip_runtime.h>
#include <stdint.h>

#define NN 100000      // nodes
#define EE 500000      // edges
#define HIDD 256
#define LN_EPS 1e-5f

typedef _Float16 half8 __attribute__((ext_vector_type(8)));  // 8 fp16 (4 VGPRs)
typedef _Float16 half4 __attribute__((ext_vector_type(4)));
typedef __fp16 fp16x2 __attribute__((ext_vector_type(2)));   // builtin return type
typedef float f32x4 __attribute__((ext_vector_type(4)));

__device__ __forceinline__ unsigned short f2h(float f) {
  _Float16 h = (_Float16)f;                 // v_cvt_f16_f32, RNE
  union { _Float16 hh; unsigned short us; } u; u.hh = h;
  return u.us;
}

__device__ __forceinline__ unsigned pkrtz(float a, float b) {
  union { fp16x2 h; unsigned u; } c;
  c.h = __builtin_amdgcn_cvt_pkrtz(a, b);   // 1 instr: 2×f32 -> packed fp16
  return c.u;
}

__device__ __forceinline__ float fast_silu(float y) {
  float e = __expf(-y);
  return y * __builtin_amdgcn_rcpf(1.f + e);     // rcp instead of full div
}

__device__ __forceinline__ void g2l16(void* lds, const void* g) {
  __builtin_amdgcn_global_load_lds(
      (const __attribute__((address_space(1))) unsigned int*)g,
      (__attribute__((address_space(3))) unsigned int*)lds, 16, 0, 0);
}

// ---- merged prep: weight swizzle (blocks 0..711) + h f32->fp16 (blocks 712..13211) ----
__global__ __launch_bounds__(256) void prep_kern(const float* __restrict__ h,
                                                 const float* __restrict__ W1,
                                                 const float* __restrict__ W2,
                                                 const float* __restrict__ W3,
                                                 unsigned short* __restrict__ hb,
                                                 unsigned short* __restrict__ w1sw,
                                                 unsigned short* __restrict__ w2sw,
                                                 unsigned short* __restrict__ w3sw) {
  int b = blockIdx.x;
  if (b < 712) {
    int t = b * 256 + threadIdx.x;
    if (t < 147456) {
      int chunk = t >> 14, rem = t & 16383;
      int kq = rem >> 11, n = (rem >> 3) & 255, j = rem & 7;
      int k = (chunk << 6) + (kq << 3) + j;
      float v = (k < 551) ? W1[k * 256 + n] : 0.f;
      w1sw[t] = f2h(v);
    } else if (t < 147456 + 32768) {
      int t2 = t - 147456;
      int chunk = t2 >> 13, rem = t2 & 8191;
      int kq = rem >> 10, n = (rem >> 3) & 127, j = rem & 7;
      int k = (chunk << 6) + (kq << 3) + j;
      w2sw[t2] = f2h(W2[k * 128 + n]);
    } else if (t < 147456 + 32768 + 2048) {
      int t3 = t - 180224;
      int kq = t3 >> 7, o = (t3 >> 3) & 15, j = t3 & 7;
      int k = (kq << 3) + j;
      w3sw[t3] = f2h((o < 5) ? W3[k * 5 + o] : 0.f);
    }
  } else {
    int i = ((b - 712) * 256 + threadIdx.x) * 8;   // N*HID = 25.6M = 12500*256*8
    float4 v0 = *(const float4*)(h + i);
    float4 v1 = *(const float4*)(h + i + 4);
    uint4 u;
    u.x = pkrtz(v0.x, v0.y); u.y = pkrtz(v0.z, v0.w);
    u.z = pkrtz(v1.x, v1.y); u.w = pkrtz(v1.z, v1.w);
    *(uint4*)(hb + i) = u;
  }
}

// ---- fused main kernel: 64 edges per block, 256 threads (4 waves) ----
// GEMMs transposed: z1^T = W1^T (A) * feats^T (B).
// A-frag: A[m=lane&15][k=(lane>>4)*8+j];  B-frag: B[k=(lane>>4)*8+j][n=lane&15]
// D: row m=(lane>>4)*4+reg (channel), col n=lane&15 (edge)
// feats/z1T/z2T XOR-swizzled: elem(row,k) at row*S + (k ^ ((row&7)<<3)).
// redS/redQ overlay r2 head (dead phases) — barriers added around their use.
struct __align__(16) SMem {
  short r1[16384];    // 32768B: A1 chunk / z1T [64][256]swz / w3s at +2048el
  short r2[8192];     // 16384B: feats / red / A2 chunk / red2 / z2T [64][128]swz
  _Float16 b1h[256], g1h[256], be1h[256];   // 1536B
  _Float16 b2h[128], g2h[128], be2h[128];   // 768B
  float muv[16];      // 64B
  float b3v[8];       // 32B
  int spI[64], exI[64];                     // 512B
};  // 52064 B -> 3 blocks/CU with 7.6KB slack

__global__ __launch_bounds__(256, 3)
void edge_head_main(const float* __restrict__ h, const float* __restrict__ x,
                    const int* __restrict__ spawn, const int* __restrict__ exist,
                    const float* __restrict__ insx, const int* __restrict__ insa,
                    const int* __restrict__ insc,
                    const float* __restrict__ b1, const float* __restrict__ g1,
                    const float* __restrict__ be1,
                    const float* __restrict__ b2, const float* __restrict__ g2,
                    const float* __restrict__ be2,
                    const float* __restrict__ b3, const float* __restrict__ mu,
                    const float* __restrict__ gammaP,
                    const unsigned short* __restrict__ w1sw,
                    const unsigned short* __restrict__ w2sw,
                    const unsigned short* __restrict__ w3swg,
                    const unsigned short* __restrict__ hb, int use_hb,
                    float* __restrict__ out) {
  __shared__ SMem sm;
  float* red = (float*)sm.r2;      // 512 floats overlaying r2 head
  const int t = threadIdx.x;
  const int base = blockIdx.x * 64;
  const int lane = t & 63;
  const int wv = t >> 6;
  const int cl = lane & 15;
  const int q = lane >> 4;
  const int sx = (cl & 7) << 3;    // B-frag read swizzle term

  // ---- const staging ----
  sm.b1h[t] = (_Float16)b1[t]; sm.g1h[t] = (_Float16)g1[t]; sm.be1h[t] = (_Float16)be1[t];
  if (t < 128) { sm.b2h[t] = (_Float16)b2[t]; sm.g2h[t] = (_Float16)g2[t]; sm.be2h[t] = (_Float16)be2[t]; }
  if (t < 16) sm.muv[t] = mu[t];
  if (t < 8) sm.b3v[t] = (t < 5) ? b3[t] : 0.f;
  if (t < 64) {
    int e = base + t; int ec = e < EE ? e : EE - 1;
    sm.spI[t] = spawn[ec]; sm.exI[t] = exist[ec];
  }
  const float gma = gammaP[0];

  __syncthreads();   // B0: indices + muv visible

  // ---- precompute chunk-8 features into registers (t<64) ----
  int4 f8a = {0,0,0,0}, f8b = {0,0,0,0};
  int k1 = 16, k2 = 32;
  if (t < 64) {
    int e = base + t; int ec = e < EE ? e : EE - 1;
    float ix0 = insx[ec * 3], ix1 = insx[ec * 3 + 1], ix2 = insx[ec * 3 + 2];
    int nd = sm.exI[t];
    float dx = ix0 - x[nd * 3], dy = ix1 - x[nd * 3 + 1], dz = ix2 - x[nd * 3 + 2];
    float d = fmaxf(sqrtf(dx * dx + dy * dy + dz * dz), 1e-6f);
    k1 = 16 + insa[ec]; k2 = 32 + insc[ec];
    float rb[16];
#pragma unroll
    for (int k = 0; k < 16; ++k) { float dd = d - sm.muv[k]; rb[k] = __expf(-gma * dd * dd); }
    uint4 ua, ub;
    ua.x = pkrtz(rb[0], rb[1]);  ua.y = pkrtz(rb[2], rb[3]);
    ua.z = pkrtz(rb[4], rb[5]);  ua.w = pkrtz(rb[6], rb[7]);
    ub.x = pkrtz(rb[8], rb[9]);  ub.y = pkrtz(rb[10], rb[11]);
    ub.z = pkrtz(rb[12], rb[13]); ub.w = pkrtz(rb[14], rb[15]);
    f8a = *(int4*)&ua; f8b = *(int4*)&ub;
  }

  // gather slots: thread fills feats rows row0 (16B piece p0) and row1
  const int row0 = t >> 3, p0 = t & 7;
  const int row1 = row0 + 32;
  const int sw0 = ((p0 ^ (row0 & 7)) << 3);
  const int sw1 = ((p0 ^ (row1 & 7)) << 3);

  int4 pA, pB;
  if (use_hb) {   // prefetch chunk 0 (spawn, colb=0)
    pA = *(const int4*)(hb + (size_t)sm.spI[row0] * HIDD + p0 * 8);
    pB = *(const int4*)(hb + (size_t)sm.spI[row1] * HIDD + p0 * 8);
  }

  // ---- GEMM1: z1^T[256][64] = W1^T * feats^T, K = 576 in 9 chunks of 64 ----
  f32x4 acc[4][4];
#pragma unroll
  for (int i = 0; i < 4; ++i)
#pragma unroll
    for (int j = 0; j < 4; ++j) acc[i][j] = (f32x4){0.f, 0.f, 0.f, 0.f};

  for (int c = 0; c < 9; ++c) {
    __syncthreads();   // prev chunk's reads done
    const unsigned short* gsrc = w1sw + c * 16384;
#pragma unroll
    for (int i = 0; i < 8; ++i)
      g2l16(&sm.r1[(i * 256 + t) * 8], gsrc + (i * 256 + t) * 8);
    if (c < 8) {
      if (use_hb) {
        *(int4*)&sm.r2[row0 * 64 + sw0] = pA;
        *(int4*)&sm.r2[row1 * 64 + sw1] = pB;
        if (c < 7) {
          const int cn = c + 1;
          const int* sel = (cn < 4) ? sm.spI : sm.exI;
          const int colb = (cn & 3) * 64;
          pA = *(const int4*)(hb + (size_t)sel[row0] * HIDD + colb + p0 * 8);
          pB = *(const int4*)(hb + (size_t)sel[row1] * HIDD + colb + p0 * 8);
        }
      } else {
        const int* sel = (c < 4) ? sm.spI : sm.exI;
        const int colb = (c & 3) * 64;
#pragma unroll
        for (int i = 0; i < 2; ++i) {
          int jj = t + i * 256;
          int row = jj >> 3, p = jj & 7;
          const float* s = h + (size_t)sel[row] * HIDD + colb + p * 8;
          float4 v0 = *(const float4*)s, v1 = *(const float4*)(s + 4);
          uint4 u;
          u.x = pkrtz(v0.x, v0.y); u.y = pkrtz(v0.z, v0.w);
          u.z = pkrtz(v1.x, v1.y); u.w = pkrtz(v1.z, v1.w);
          *(uint4*)&sm.r2[row * 64 + ((p ^ (row & 7)) << 3)] = u;
        }
      }
    } else {
      // chunk 8 from precomputed regs: 8×b128 + 2×b16 per owning thread
      if (t < 64) {
        short* rp = &sm.r2[t * 64];
        const int sw = t & 7;
#pragma unroll
        for (int g = 0; g < 8; ++g) {
          int4 v = (g == 0) ? f8a : (g == 1) ? f8b : (int4){0,0,0,0};
          *(int4*)&rp[(g ^ sw) * 8] = v;
        }
        rp[((k1 >> 3) ^ sw) * 8 + (k1 & 7)] = (short)0x3C00;   // fp16 1.0
        rp[((k2 >> 3) ^ sw) * 8 + (k2 & 7)] = (short)0x3C00;
      }
    }
    __syncthreads();
#pragma unroll
    for (int ks = 0; ks < 2; ++ks) {
      half8 af[4], bf[4];
#pragma unroll
      for (int i = 0; i < 4; ++i)
        af[i] = *(const half8*)&sm.r1[(ks * 4 + q) * 2048 + (wv * 64 + i * 16 + cl) * 8];
#pragma unroll
      for (int j = 0; j < 4; ++j)
        bf[j] = *(const half8*)&sm.r2[(j * 16 + cl) * 64 + ((ks * 32 + q * 8) ^ sx)];
#pragma unroll
      for (int i = 0; i < 4; ++i)
#pragma unroll
        for (int j = 0; j < 4; ++j)
          acc[i][j] = __builtin_amdgcn_mfma_f32_16x16x32_f16(af[i], bf[j], acc[i][j], 0, 0, 0);
    }
  }

  // ---- +b1 (fused), LN over 256 channels, SiLU, pack to z1T ----
  float bf1[4][4];
#pragma unroll
  for (int i = 0; i < 4; ++i) {
    half4 b4 = *(const half4*)&sm.b1h[wv * 64 + i * 16 + q * 4];
#pragma unroll
    for (int r = 0; r < 4; ++r) bf1[i][r] = (float)b4[r];
  }
  float S1arr[4], Q1arr[4];
#pragma unroll
  for (int j = 0; j < 4; ++j) {
    float S = 0.f, Q = 0.f;
#pragma unroll
    for (int i = 0; i < 4; ++i)
#pragma unroll
      for (int r = 0; r < 4; ++r) {
        float v = acc[i][j][r] + bf1[i][r];
        acc[i][j][r] = v; S += v; Q += v * v;
      }
    S += __shfl_xor(S, 16); S += __shfl_xor(S, 32);
    Q += __shfl_xor(Q, 16); Q += __shfl_xor(Q, 32);
    S1arr[j] = S; Q1arr[j] = Q;
  }
  __syncthreads();   // B3: final MFMA reads of r1/r2 done -> red overlay + z1T safe
  if (q == 0) {
#pragma unroll
    for (int j = 0; j < 4; ++j) {
      red[wv * 64 + j * 16 + cl] = S1arr[j];
      red[256 + wv * 64 + j * 16 + cl] = Q1arr[j];
    }
  }
  __syncthreads();   // B4: red1 visible
  float mean1[4], rstd1[4];
#pragma unroll
  for (int j = 0; j < 4; ++j) {
    int m = j * 16 + cl;
    float S = red[m] + red[64 + m] + red[128 + m] + red[192 + m];
    float Q = red[256 + m] + red[320 + m] + red[384 + m] + red[448 + m];
    float mn = S * (1.f / 256.f);
    mean1[j] = mn;
    rstd1[j] = rsqrtf(Q * (1.f / 256.f) - mn * mn + LN_EPS);
  }
#pragma unroll
  for (int i = 0; i < 4; ++i) {
    half4 g4 = *(const half4*)&sm.g1h[wv * 64 + i * 16 + q * 4];
    half4 e4 = *(const half4*)&sm.be1h[wv * 64 + i * 16 + q * 4];
    float gf[4], ef[4];
#pragma unroll
    for (int r = 0; r < 4; ++r) { gf[r] = (float)g4[r]; ef[r] = (float)e4[r]; }
#pragma unroll
    for (int j = 0; j < 4; ++j) {
      float s0 = fast_silu((acc[i][j][0] - mean1[j]) * rstd1[j] * gf[0] + ef[0]);
      float s1 = fast_silu((acc[i][j][1] - mean1[j]) * rstd1[j] * gf[1] + ef[1]);
      float s2 = fast_silu((acc[i][j][2] - mean1[j]) * rstd1[j] * gf[2] + ef[2]);
      float s3 = fast_silu((acc[i][j][3] - mean1[j]) * rstd1[j] * gf[3] + ef[3]);
      uint2 w; w.x = pkrtz(s0, s1); w.y = pkrtz(s2, s3);
      int m = j * 16 + cl;
      int k0 = wv * 64 + i * 16 + q * 4;
      *(uint2*)&sm.r1[m * 256 + (k0 ^ ((m & 7) << 3))] = w;   // z1T swz
    }
  }

  // ---- GEMM2: z2^T[128][64] = W2^T * z1^T, K = 256 in 4 chunks of 64 ----
  f32x4 acc2[2][4];
#pragma unroll
  for (int i = 0; i < 2; ++i)
#pragma unroll
    for (int j = 0; j < 4; ++j) acc2[i][j] = (f32x4){0.f, 0.f, 0.f, 0.f};
  for (int c2 = 0; c2 < 4; ++c2) {
    __syncthreads();   // first iter: z1T visible + red1 reads done -> A2 over red ok
    const unsigned short* gsrc = w2sw + c2 * 8192;
#pragma unroll
    for (int i = 0; i < 4; ++i)
      g2l16(&sm.r2[(i * 256 + t) * 8], gsrc + (i * 256 + t) * 8);
    __syncthreads();
#pragma unroll
    for (int ks = 0; ks < 2; ++ks) {
      half8 af[2], bf[4];
#pragma unroll
      for (int i = 0; i < 2; ++i)
        af[i] = *(const half8*)&sm.r2[(ks * 4 + q) * 1024 + (wv * 32 + i * 16 + cl) * 8];
#pragma unroll
      for (int j = 0; j < 4; ++j)
        bf[j] = *(const half8*)&sm.r1[(j * 16 + cl) * 256 + ((c2 * 64 + ks * 32 + q * 8) ^ sx)];
#pragma unroll
      for (int i = 0; i < 2; ++i)
#pragma unroll
        for (int j = 0; j < 4; ++j)
          acc2[i][j] = __builtin_amdgcn_mfma_f32_16x16x32_f16(af[i], bf[j], acc2[i][j], 0, 0, 0);
    }
  }
  __syncthreads();   // B7: GEMM2 reads (r1 z1T, r2 A2) done

  // stage W3 fragments into dead z1T space (r1 + 2048 el), async
  g2l16(&sm.r1[2048 + t * 8], w3swg + t * 8);

  // ---- +b2 (fused), LN over 128, SiLU, pack z2T ----
  float bf2[2][4];
#pragma unroll
  for (int i = 0; i < 2; ++i) {
    half4 b4 = *(const half4*)&sm.b2h[wv * 32 + i * 16 + q * 4];
#pragma unroll
    for (int r = 0; r < 4; ++r) bf2[i][r] = (float)b4[r];
  }
  float S2arr[4], Q2arr[4];
#pragma unroll
  for (int j = 0; j < 4; ++j) {
    float S = 0.f, Q = 0.f;
#pragma unroll
    for (int i = 0; i < 2; ++i)
#pragma unroll
      for (int r = 0; r < 4; ++r) {
        float v = acc2[i][j][r] + bf2[i][r];
        acc2[i][j][r] = v; S += v; Q += v * v;
      }
    S += __shfl_xor(S, 16); S += __shfl_xor(S, 32);
    Q += __shfl_xor(Q, 16); Q += __shfl_xor(Q, 32);
    S2arr[j] = S; Q2arr[j] = Q;
  }
  if (q == 0) {
#pragma unroll
    for (int j = 0; j < 4; ++j) {
      red[wv * 64 + j * 16 + cl] = S2arr[j];        // red2 over dead A2 head
      red[256 + wv * 64 + j * 16 + cl] = Q2arr[j];
    }
  }
  __syncthreads();   // B8: red2 visible
  float mean2[4], rstd2[4];
#pragma unroll
  for (int j = 0; j < 4; ++j) {
    int m = j * 16 + cl;
    float S = red[m] + red[64 + m] + red[128 + m] + red[192 + m];
    float Q = red[256 + m] + red[320 + m] + red[384 + m] + red[448 + m];
    float mn = S * (1.f / 128.f);
    mean2[j] = mn;
    rstd2[j] = rsqrtf(Q * (1.f / 128.f) - mn * mn + LN_EPS);
  }
  __syncthreads();   // B9: all red2 reads done -> z2T may overwrite r2 head
#pragma unroll
  for (int i = 0; i < 2; ++i) {
    half4 g4 = *(const half4*)&sm.g2h[wv * 32 + i * 16 + q * 4];
    half4 e4 = *(const half4*)&sm.be2h[wv * 32 + i * 16 + q * 4];
    float gf[4], ef[4];
#pragma unroll
    for (int r = 0; r < 4; ++r) { gf[r] = (float)g4[r]; ef[r] = (float)e4[r]; }
#pragma unroll
    for (int j = 0; j < 4; ++j) {
      float s0 = fast_silu((acc2[i][j][0] - mean2[j]) * rstd2[j] * gf[0] + ef[0]);
      float s1 = fast_silu((acc2[i][j][1] - mean2[j]) * rstd2[j] * gf[1] + ef[1]);
      float s2 = fast_silu((acc2[i][j][2] - mean2[j]) * rstd2[j] * gf[2] + ef[2]);
      float s3 = fast_silu((acc2[i][j][3] - mean2[j]) * rstd2[j] * gf[3] + ef[3]);
      uint2 w; w.x = pkrtz(s0, s1); w.y = pkrtz(s2, s3);
      int m = j * 16 + cl;
      int k0 = wv * 32 + i * 16 + q * 4;
      *(uint2*)&sm.r2[m * 128 + (k0 ^ ((m & 7) << 3))] = w;   // z2T swz
    }
  }
  __syncthreads();   // B10: z2T + w3s visible

  // ---- GEMM3: out^T[16][64] = W3^T * z2^T (o padded 5->16) ----
  f32x4 a3 = (f32x4){0.f, 0.f, 0.f, 0.f};
  const int m3 = wv * 16 + cl;
  const int sx3 = (m3 & 7) << 3;
#pragma unroll
  for (int ks = 0; ks < 4; ++ks) {
    half8 af = *(const half8*)&sm.r1[2048 + (ks * 4 + q) * 128 + cl * 8];
    half8 bf = *(const half8*)&sm.r2[m3 * 128 + ((ks * 32 + q * 8) ^ sx3)];
    a3 = __builtin_amdgcn_mfma_f32_16x16x32_f16(af, bf, a3, 0, 0, 0);
  }
  int e = base + m3;
  if (e < EE) {
#pragma unroll
    for (int r = 0; r < 4; ++r) {
      int o = q * 4 + r;
      if (o < 5) out[e * 5 + o] = a3[r] + sm.b3v[o];
    }
  }
}

extern "C" void kernel_launch(void* const* d_in, const int* in_sizes, int n_in,
                              void* d_out, int out_size, void* d_ws, size_t ws_size,
                              hipStream_t stream) {
  const float* h    = (const float*)d_in[0];
  const float* x    = (const float*)d_in[1];
  const int* spawn  = (const int*)d_in[2];
  const int* exist  = (const int*)d_in[3];
  const float* insx = (const float*)d_in[4];
  const int* insa   = (const int*)d_in[5];
  const int* insc   = (const int*)d_in[6];
  const float* W1   = (const float*)d_in[7];
  const float* b1   = (const float*)d_in[8];
  const float* g1   = (const float*)d_in[9];
  const float* be1  = (const float*)d_in[10];
  const float* W2   = (const float*)d_in[11];
  const float* b2   = (const float*)d_in[12];
  const float* g2   = (const float*)d_in[13];
  const float* be2  = (const float*)d_in[14];
  const float* W3   = (const float*)d_in[15];
  const float* b3   = (const float*)d_in[16];
  const float* mu   = (const float*)d_in[17];
  const float* gma  = (const float*)d_in[18];

  unsigned short* w1sw = (unsigned short*)d_ws;          // 147456 el
  unsigned short* w2sw = w1sw + 147456;                  // 32768 el
  unsigned short* w3sw = w2sw + 32768;                   // 2048 el
  unsigned short* hb   = w3sw + 2048;                    // N*HID el (optional)
  const size_t need_hb = 364544ull + (size_t)NN * HIDD * 2ull;
  int use_hb = (ws_size >= need_hb) ? 1 : 0;

  prep_kern<<<use_hb ? 13212 : 712, 256, 0, stream>>>(h, W1, W2, W3, hb, w1sw, w2sw, w3sw);
  edge_head_main<<<7813, 256, 0, stream>>>(h, x, spawn, exist, insx, insa, insc,
                                           b1, g1, be1, b2, g2, be2, b3, mu, gma,
                                           w1sw, w2sw, w3sw, hb, use_hb,
                                           (float*)d_out);
}

// Round 7
// 418.301 us; speedup vs baseline: 1.4174x; 1.1074x over previous
//
#include <hip/hip_runtime.h>
#include <stdint.h>

#define NN 100000      // nodes
#define EE 500000      // edges
#define HIDD 256
#define LN_EPS 1e-5f

typedef _Float16 half8 __attribute__((ext_vector_type(8)));  // 8 fp16 (4 VGPRs)
typedef _Float16 half4 __attribute__((ext_vector_type(4)));
typedef __fp16 fp16x2 __attribute__((ext_vector_type(2)));   // builtin return type
typedef float f32x4 __attribute__((ext_vector_type(4)));

// lgkm-only barrier: makes LDS writes visible WITHOUT draining vmcnt (global loads
// stay in flight across it — the fine-grained vmcnt pattern __syncthreads forbids).
#define LBAR() asm volatile("s_waitcnt lgkmcnt(0)\n\ts_barrier" ::: "memory")

__device__ __forceinline__ unsigned short f2h(float f) {
  _Float16 h = (_Float16)f;                 // v_cvt_f16_f32, RNE
  union { _Float16 hh; unsigned short us; } u; u.hh = h;
  return u.us;
}

__device__ __forceinline__ unsigned pkrtz(float a, float b) {
  union { fp16x2 h; unsigned u; } c;
  c.h = __builtin_amdgcn_cvt_pkrtz(a, b);   // 1 instr: 2×f32 -> packed fp16
  return c.u;
}

__device__ __forceinline__ float fast_silu(float y) {
  float e = __expf(-y);
  return y * __builtin_amdgcn_rcpf(1.f + e);     // rcp instead of full div
}

__device__ __forceinline__ half8 ldg8(const unsigned short* p) {
  return *(const half8*)p;                  // global_load_dwordx4
}

// ---- merged prep: weight swizzle (blocks 0..711) + h f32->fp16 (blocks 712..13211) ----
__global__ __launch_bounds__(256) void prep_kern(const float* __restrict__ h,
                                                 const float* __restrict__ W1,
                                                 const float* __restrict__ W2,
                                                 const float* __restrict__ W3,
                                                 unsigned short* __restrict__ hb,
                                                 unsigned short* __restrict__ w1sw,
                                                 unsigned short* __restrict__ w2sw,
                                                 unsigned short* __restrict__ w3sw) {
  int b = blockIdx.x;
  if (b < 712) {
    int t = b * 256 + threadIdx.x;
    if (t < 147456) {
      int chunk = t >> 14, rem = t & 16383;
      int kq = rem >> 11, n = (rem >> 3) & 255, j = rem & 7;
      int k = (chunk << 6) + (kq << 3) + j;
      float v = (k < 551) ? W1[k * 256 + n] : 0.f;
      w1sw[t] = f2h(v);
    } else if (t < 147456 + 32768) {
      int t2 = t - 147456;
      int chunk = t2 >> 13, rem = t2 & 8191;
      int kq = rem >> 10, n = (rem >> 3) & 127, j = rem & 7;
      int k = (chunk << 6) + (kq << 3) + j;
      w2sw[t2] = f2h(W2[k * 128 + n]);
    } else if (t < 147456 + 32768 + 2048) {
      int t3 = t - 180224;
      int kq = t3 >> 7, o = (t3 >> 3) & 15, j = t3 & 7;
      int k = (kq << 3) + j;
      w3sw[t3] = f2h((o < 5) ? W3[k * 5 + o] : 0.f);
    }
  } else {
    int i = ((b - 712) * 256 + threadIdx.x) * 8;   // N*HID = 25.6M = 12500*256*8
    float4 v0 = *(const float4*)(h + i);
    float4 v1 = *(const float4*)(h + i + 4);
    uint4 u;
    u.x = pkrtz(v0.x, v0.y); u.y = pkrtz(v0.z, v0.w);
    u.z = pkrtz(v1.x, v1.y); u.w = pkrtz(v1.z, v1.w);
    *(uint4*)(hb + i) = u;
  }
}

// ---- fused main kernel: 64 edges/block, 256 threads (4 waves), 3 blocks/CU ----
// W1/W2/W3 fragments load DIRECTLY global->VGPR (zero intra-block sharing; L1/L2
// serve cross-block reuse). LDS holds only block-local data: feats dbuf, z1T, z2T.
// All barriers are lgkm-only — global loads are never force-drained.
// A-frag: A[m=lane&15][k=(lane>>4)*8+j];  B-frag: B[k=(lane>>4)*8+j][n=lane&15]
// D: row m=(lane>>4)*4+reg (channel), col n=lane&15 (edge)
// feats/z1T/z2T XOR-swizzled: elem(row,k) at row*S + (k ^ ((row&7)<<3)).
struct __align__(16) SMem {
  short r1[16384];    // 32768B: feats dbuf (2x4096el) in GEMM1 -> z1T [64][256]swz -> z2T [64][128]swz (head)
  float red[512];     // 2048B : LN partial sums (S in [0..255], Q in [256..511])
  _Float16 b1h[256], g1h[256], be1h[256];   // 1536B
  _Float16 b2h[128], g2h[128], be2h[128];   // 768B
  float muv[16];      // 64B
  float b3v[8];       // 32B
  int spI[64], exI[64];                     // 512B
};  // ~37.7 KB

__global__ __launch_bounds__(256, 3)
void edge_head_main(const float* __restrict__ h, const float* __restrict__ x,
                    const int* __restrict__ spawn, const int* __restrict__ exist,
                    const float* __restrict__ insx, const int* __restrict__ insa,
                    const int* __restrict__ insc,
                    const float* __restrict__ b1, const float* __restrict__ g1,
                    const float* __restrict__ be1,
                    const float* __restrict__ b2, const float* __restrict__ g2,
                    const float* __restrict__ be2,
                    const float* __restrict__ b3, const float* __restrict__ mu,
                    const float* __restrict__ gammaP,
                    const unsigned short* __restrict__ w1sw,
                    const unsigned short* __restrict__ w2sw,
                    const unsigned short* __restrict__ w3swg,
                    const unsigned short* __restrict__ hb, int use_hb,
                    float* __restrict__ out) {
  __shared__ SMem sm;
  const int t = threadIdx.x;
  const int base = blockIdx.x * 64;
  const int lane = t & 63;
  const int wv = t >> 6;
  const int cl = lane & 15;
  const int q = lane >> 4;
  const int sx = (cl & 7) << 3;    // B-frag read swizzle term

  // ---- const staging ----
  sm.b1h[t] = (_Float16)b1[t]; sm.g1h[t] = (_Float16)g1[t]; sm.be1h[t] = (_Float16)be1[t];
  if (t < 128) { sm.b2h[t] = (_Float16)b2[t]; sm.g2h[t] = (_Float16)g2[t]; sm.be2h[t] = (_Float16)be2[t]; }
  if (t < 16) sm.muv[t] = mu[t];
  if (t < 8) sm.b3v[t] = (t < 5) ? b3[t] : 0.f;
  if (t < 64) {
    int e = base + t; int ec = e < EE ? e : EE - 1;
    sm.spI[t] = spawn[ec]; sm.exI[t] = exist[ec];
  }
  const float gma = gammaP[0];

  LBAR();   // B0: indices + consts visible

  // ---- precompute chunk-8 features into registers (t<64) ----
  int4 f8a = {0,0,0,0}, f8b = {0,0,0,0};
  int k1 = 16, k2 = 32;
  if (t < 64) {
    int e = base + t; int ec = e < EE ? e : EE - 1;
    float ix0 = insx[ec * 3], ix1 = insx[ec * 3 + 1], ix2 = insx[ec * 3 + 2];
    int nd = sm.exI[t];
    float dx = ix0 - x[nd * 3], dy = ix1 - x[nd * 3 + 1], dz = ix2 - x[nd * 3 + 2];
    float d = fmaxf(sqrtf(dx * dx + dy * dy + dz * dz), 1e-6f);
    k1 = 16 + insa[ec]; k2 = 32 + insc[ec];
    float rb[16];
#pragma unroll
    for (int k = 0; k < 16; ++k) { float dd = d - sm.muv[k]; rb[k] = __expf(-gma * dd * dd); }
    uint4 ua, ub;
    ua.x = pkrtz(rb[0], rb[1]);  ua.y = pkrtz(rb[2], rb[3]);
    ua.z = pkrtz(rb[4], rb[5]);  ua.w = pkrtz(rb[6], rb[7]);
    ub.x = pkrtz(rb[8], rb[9]);  ub.y = pkrtz(rb[10], rb[11]);
    ub.z = pkrtz(rb[12], rb[13]); ub.w = pkrtz(rb[14], rb[15]);
    f8a = *(int4*)&ua; f8b = *(int4*)&ub;
  }

  // gather slots: thread fills feats rows row0 (16B piece p0) and row1 (=row0+32)
  const int row0 = t >> 3, p0 = t & 7;
  const int row1 = row0 + 32;
  const int sw0 = ((p0 ^ (row0 & 7)) << 3);
  const int sw1 = ((p0 ^ (row1 & 7)) << 3);

  // chunk 0 gather (spawn, colb=0)
  int4 pA, pB;
  if (use_hb) {
    pA = *(const int4*)(hb + (size_t)sm.spI[row0] * HIDD + p0 * 8);
    pB = *(const int4*)(hb + (size_t)sm.spI[row1] * HIDD + p0 * 8);
  } else {
    const float* sA = h + (size_t)sm.spI[row0] * HIDD + p0 * 8;
    const float* sB = h + (size_t)sm.spI[row1] * HIDD + p0 * 8;
    float4 a0 = *(const float4*)sA, a1 = *(const float4*)(sA + 4);
    float4 b0 = *(const float4*)sB, b1v_ = *(const float4*)(sB + 4);
    uint4 ua, ub;
    ua.x = pkrtz(a0.x, a0.y); ua.y = pkrtz(a0.z, a0.w); ua.z = pkrtz(a1.x, a1.y); ua.w = pkrtz(a1.z, a1.w);
    ub.x = pkrtz(b0.x, b0.y); ub.y = pkrtz(b0.z, b0.w); ub.z = pkrtz(b1v_.x, b1v_.y); ub.w = pkrtz(b1v_.z, b1v_.w);
    pA = *(int4*)&ua; pB = *(int4*)&ub;
  }
  // write chunk 0 -> buf0
  *(int4*)&sm.r1[row0 * 64 + sw0] = pA;
  *(int4*)&sm.r1[row1 * 64 + sw1] = pB;
  // issue chunk 1 gather (spawn, colb=64)
  if (use_hb) {
    pA = *(const int4*)(hb + (size_t)sm.spI[row0] * HIDD + 64 + p0 * 8);
    pB = *(const int4*)(hb + (size_t)sm.spI[row1] * HIDD + 64 + p0 * 8);
  } else {
    const float* sA = h + (size_t)sm.spI[row0] * HIDD + 64 + p0 * 8;
    const float* sB = h + (size_t)sm.spI[row1] * HIDD + 64 + p0 * 8;
    float4 a0 = *(const float4*)sA, a1 = *(const float4*)(sA + 4);
    float4 b0 = *(const float4*)sB, b1v_ = *(const float4*)(sB + 4);
    uint4 ua, ub;
    ua.x = pkrtz(a0.x, a0.y); ua.y = pkrtz(a0.z, a0.w); ua.z = pkrtz(a1.x, a1.y); ua.w = pkrtz(a1.z, a1.w);
    ub.x = pkrtz(b0.x, b0.y); ub.y = pkrtz(b0.z, b0.w); ub.z = pkrtz(b1v_.x, b1v_.y); ub.w = pkrtz(b1v_.z, b1v_.w);
    pA = *(int4*)&ua; pB = *(int4*)&ub;
  }

  // W1 fragment base for this thread (direct global->reg)
  const unsigned short* w1p = w1sw + q * 2048 + wv * 512 + cl * 8;
  half8 fcur[8], fnext[8];
#pragma unroll
  for (int ks = 0; ks < 2; ++ks)
#pragma unroll
    for (int i = 0; i < 4; ++i)
      fcur[ks * 4 + i] = ldg8(w1p + ks * 8192 + i * 128);

  LBAR();   // buf0 visible

  // ---- GEMM1: z1^T[256][64] = W1^T * feats^T, K = 576 in 9 chunks of 64 ----
  f32x4 acc[4][4];
#pragma unroll
  for (int i = 0; i < 4; ++i)
#pragma unroll
    for (int j = 0; j < 4; ++j) acc[i][j] = (f32x4){0.f, 0.f, 0.f, 0.f};

#pragma unroll
  for (int c = 0; c < 9; ++c) {
    // stage feats chunk c+1 into buf[(c+1)&1]; prefetch chunk c+2
    if (c < 7) {
      const int nb = ((c + 1) & 1) * 4096;
      *(int4*)&sm.r1[nb + row0 * 64 + sw0] = pA;   // vmcnt wait auto (data dep)
      *(int4*)&sm.r1[nb + row1 * 64 + sw1] = pB;
      if (c < 6) {
        const int cn = c + 2;
        const int* sel = (cn < 4) ? sm.spI : sm.exI;
        const int colb = (cn & 3) * 64;
        if (use_hb) {
          pA = *(const int4*)(hb + (size_t)sel[row0] * HIDD + colb + p0 * 8);
          pB = *(const int4*)(hb + (size_t)sel[row1] * HIDD + colb + p0 * 8);
        } else {
          const float* sA = h + (size_t)sel[row0] * HIDD + colb + p0 * 8;
          const float* sB = h + (size_t)sel[row1] * HIDD + colb + p0 * 8;
          float4 a0 = *(const float4*)sA, a1 = *(const float4*)(sA + 4);
          float4 b0 = *(const float4*)sB, b1v_ = *(const float4*)(sB + 4);
          uint4 ua, ub;
          ua.x = pkrtz(a0.x, a0.y); ua.y = pkrtz(a0.z, a0.w); ua.z = pkrtz(a1.x, a1.y); ua.w = pkrtz(a1.z, a1.w);
          ub.x = pkrtz(b0.x, b0.y); ub.y = pkrtz(b0.z, b0.w); ub.z = pkrtz(b1v_.x, b1v_.y); ub.w = pkrtz(b1v_.z, b1v_.w);
          pA = *(int4*)&ua; pB = *(int4*)&ub;
        }
      }
    } else if (c == 7) {
      // chunk 8 = built features -> buf0, from precomputed regs
      if (t < 64) {
        short* rp = &sm.r1[t * 64];   // (8&1)=0 -> buf0
        const int sw = t & 7;
#pragma unroll
        for (int g = 0; g < 8; ++g) {
          int4 v = (g == 0) ? f8a : (g == 1) ? f8b : (int4){0, 0, 0, 0};
          *(int4*)&rp[(g ^ sw) * 8] = v;
        }
        rp[((k1 >> 3) ^ sw) * 8 + (k1 & 7)] = (short)0x3C00;   // fp16 1.0
        rp[((k2 >> 3) ^ sw) * 8 + (k2 & 7)] = (short)0x3C00;
      }
    }
    // prefetch W1 frags for chunk c+1 (regs)
    if (c < 8) {
      const unsigned short* wp = w1p + (c + 1) * 16384;
#pragma unroll
      for (int ks = 0; ks < 2; ++ks)
#pragma unroll
        for (int i = 0; i < 4; ++i)
          fnext[ks * 4 + i] = ldg8(wp + ks * 8192 + i * 128);
    }
    // MFMA chunk c from buf[c&1] + fcur
    const int cb = (c & 1) * 4096;
#pragma unroll
    for (int ks = 0; ks < 2; ++ks) {
      half8 bf[4];
#pragma unroll
      for (int j = 0; j < 4; ++j)
        bf[j] = *(const half8*)&sm.r1[cb + (j * 16 + cl) * 64 + ((ks * 32 + q * 8) ^ sx)];
#pragma unroll
      for (int i = 0; i < 4; ++i)
#pragma unroll
        for (int j = 0; j < 4; ++j)
          acc[i][j] = __builtin_amdgcn_mfma_f32_16x16x32_f16(fcur[ks * 4 + i], bf[j], acc[i][j], 0, 0, 0);
    }
#pragma unroll
    for (int u = 0; u < 8; ++u) fcur[u] = fnext[u];
    LBAR();   // chunk c+1 writes visible; all waves done with buf[c&1]
  }

  // ---- +b1 (fused), LN over 256 channels, SiLU, pack to z1T ----
  float bf1[4][4];
#pragma unroll
  for (int i = 0; i < 4; ++i) {
    half4 b4 = *(const half4*)&sm.b1h[wv * 64 + i * 16 + q * 4];
#pragma unroll
    for (int r = 0; r < 4; ++r) bf1[i][r] = (float)b4[r];
  }
  float S1arr[4], Q1arr[4];
#pragma unroll
  for (int j = 0; j < 4; ++j) {
    float S = 0.f, Q = 0.f;
#pragma unroll
    for (int i = 0; i < 4; ++i)
#pragma unroll
      for (int r = 0; r < 4; ++r) {
        float v = acc[i][j][r] + bf1[i][r];
        acc[i][j][r] = v; S += v; Q += v * v;
      }
    S += __shfl_xor(S, 16); S += __shfl_xor(S, 32);
    Q += __shfl_xor(Q, 16); Q += __shfl_xor(Q, 32);
    S1arr[j] = S; Q1arr[j] = Q;
  }
  if (q == 0) {
#pragma unroll
    for (int j = 0; j < 4; ++j) {
      sm.red[wv * 64 + j * 16 + cl] = S1arr[j];
      sm.red[256 + wv * 64 + j * 16 + cl] = Q1arr[j];
    }
  }
  LBAR();   // red1 visible; all waves past GEMM1 -> r1 reusable as z1T
  float mean1[4], rstd1[4];
#pragma unroll
  for (int j = 0; j < 4; ++j) {
    int m = j * 16 + cl;
    float S = sm.red[m] + sm.red[64 + m] + sm.red[128 + m] + sm.red[192 + m];
    float Q = sm.red[256 + m] + sm.red[320 + m] + sm.red[384 + m] + sm.red[448 + m];
    float mn = S * (1.f / 256.f);
    mean1[j] = mn;
    rstd1[j] = rsqrtf(Q * (1.f / 256.f) - mn * mn + LN_EPS);
  }
#pragma unroll
  for (int i = 0; i < 4; ++i) {
    half4 g4 = *(const half4*)&sm.g1h[wv * 64 + i * 16 + q * 4];
    half4 e4 = *(const half4*)&sm.be1h[wv * 64 + i * 16 + q * 4];
    float gf[4], ef[4];
#pragma unroll
    for (int r = 0; r < 4; ++r) { gf[r] = (float)g4[r]; ef[r] = (float)e4[r]; }
#pragma unroll
    for (int j = 0; j < 4; ++j) {
      float s0 = fast_silu((acc[i][j][0] - mean1[j]) * rstd1[j] * gf[0] + ef[0]);
      float s1 = fast_silu((acc[i][j][1] - mean1[j]) * rstd1[j] * gf[1] + ef[1]);
      float s2 = fast_silu((acc[i][j][2] - mean1[j]) * rstd1[j] * gf[2] + ef[2]);
      float s3 = fast_silu((acc[i][j][3] - mean1[j]) * rstd1[j] * gf[3] + ef[3]);
      uint2 w; w.x = pkrtz(s0, s1); w.y = pkrtz(s2, s3);
      int m = j * 16 + cl;
      int k0 = wv * 64 + i * 16 + q * 4;
      *(uint2*)&sm.r1[m * 256 + (k0 ^ ((m & 7) << 3))] = w;   // z1T swz
    }
  }
  LBAR();   // z1T visible

  // W3 fragments: issue early, consumed at GEMM3 (vmcnt interleave)
  half8 af3[4];
#pragma unroll
  for (int ks = 0; ks < 4; ++ks)
    af3[ks] = ldg8(w3swg + (ks * 4 + q) * 128 + cl * 8);

  // ---- GEMM2: z2^T[128][64] = W2^T * z1^T — barrier-free, W2 direct-to-reg ----
  const unsigned short* w2p = w2sw + q * 1024 + wv * 256 + cl * 8;
  f32x4 acc2[2][4];
#pragma unroll
  for (int i = 0; i < 2; ++i)
#pragma unroll
    for (int j = 0; j < 4; ++j) acc2[i][j] = (f32x4){0.f, 0.f, 0.f, 0.f};
#pragma unroll
  for (int c2 = 0; c2 < 4; ++c2) {
#pragma unroll
    for (int ks = 0; ks < 2; ++ks) {
      half8 a0 = ldg8(w2p + c2 * 8192 + ks * 4096);
      half8 a1 = ldg8(w2p + c2 * 8192 + ks * 4096 + 128);
      half8 bf[4];
#pragma unroll
      for (int j = 0; j < 4; ++j)
        bf[j] = *(const half8*)&sm.r1[(j * 16 + cl) * 256 + ((c2 * 64 + ks * 32 + q * 8) ^ sx)];
#pragma unroll
      for (int j = 0; j < 4; ++j) {
        acc2[0][j] = __builtin_amdgcn_mfma_f32_16x16x32_f16(a0, bf[j], acc2[0][j], 0, 0, 0);
        acc2[1][j] = __builtin_amdgcn_mfma_f32_16x16x32_f16(a1, bf[j], acc2[1][j], 0, 0, 0);
      }
    }
  }

  // ---- +b2 (fused), LN over 128, SiLU, pack z2T (overlays z1T head in r1) ----
  float bf2[2][4];
#pragma unroll
  for (int i = 0; i < 2; ++i) {
    half4 b4 = *(const half4*)&sm.b2h[wv * 32 + i * 16 + q * 4];
#pragma unroll
    for (int r = 0; r < 4; ++r) bf2[i][r] = (float)b4[r];
  }
  float S2arr[4], Q2arr[4];
#pragma unroll
  for (int j = 0; j < 4; ++j) {
    float S = 0.f, Q = 0.f;
#pragma unroll
    for (int i = 0; i < 2; ++i)
#pragma unroll
      for (int r = 0; r < 4; ++r) {
        float v = acc2[i][j][r] + bf2[i][r];
        acc2[i][j][r] = v; S += v; Q += v * v;
      }
    S += __shfl_xor(S, 16); S += __shfl_xor(S, 32);
    Q += __shfl_xor(Q, 16); Q += __shfl_xor(Q, 32);
    S2arr[j] = S; Q2arr[j] = Q;
  }
  if (q == 0) {
#pragma unroll
    for (int j = 0; j < 4; ++j) {
      sm.red[wv * 64 + j * 16 + cl] = S2arr[j];
      sm.red[256 + wv * 64 + j * 16 + cl] = Q2arr[j];
    }
  }
  LBAR();   // red2 visible; all waves past GEMM2 -> z1T dead, z2T region safe
  float mean2[4], rstd2[4];
#pragma unroll
  for (int j = 0; j < 4; ++j) {
    int m = j * 16 + cl;
    float S = sm.red[m] + sm.red[64 + m] + sm.red[128 + m] + sm.red[192 + m];
    float Q = sm.red[256 + m] + sm.red[320 + m] + sm.red[384 + m] + sm.red[448 + m];
    float mn = S * (1.f / 128.f);
    mean2[j] = mn;
    rstd2[j] = rsqrtf(Q * (1.f / 128.f) - mn * mn + LN_EPS);
  }
#pragma unroll
  for (int i = 0; i < 2; ++i) {
    half4 g4 = *(const half4*)&sm.g2h[wv * 32 + i * 16 + q * 4];
    half4 e4 = *(const half4*)&sm.be2h[wv * 32 + i * 16 + q * 4];
    float gf[4], ef[4];
#pragma unroll
    for (int r = 0; r < 4; ++r) { gf[r] = (float)g4[r]; ef[r] = (float)e4[r]; }
#pragma unroll
    for (int j = 0; j < 4; ++j) {
      float s0 = fast_silu((acc2[i][j][0] - mean2[j]) * rstd2[j] * gf[0] + ef[0]);
      float s1 = fast_silu((acc2[i][j][1] - mean2[j]) * rstd2[j] * gf[1] + ef[1]);
      float s2 = fast_silu((acc2[i][j][2] - mean2[j]) * rstd2[j] * gf[2] + ef[2]);
      float s3 = fast_silu((acc2[i][j][3] - mean2[j]) * rstd2[j] * gf[3] + ef[3]);
      uint2 w; w.x = pkrtz(s0, s1); w.y = pkrtz(s2, s3);
      int m = j * 16 + cl;
      int k0 = wv * 32 + i * 16 + q * 4;
      *(uint2*)&sm.r1[m * 128 + (k0 ^ ((m & 7) << 3))] = w;   // z2T swz (r1 head)
    }
  }
  LBAR();   // z2T visible

  // ---- GEMM3: out^T[16][64] = W3^T * z2^T (o padded 5->16) ----
  f32x4 a3 = (f32x4){0.f, 0.f, 0.f, 0.f};
  const int m3 = wv * 16 + cl;
  const int sx3 = (m3 & 7) << 3;
#pragma unroll
  for (int ks = 0; ks < 4; ++ks) {
    half8 bf = *(const half8*)&sm.r1[m3 * 128 + ((ks * 32 + q * 8) ^ sx3)];
    a3 = __builtin_amdgcn_mfma_f32_16x16x32_f16(af3[ks], bf, a3, 0, 0, 0);
  }
  int e = base + m3;
  if (e < EE) {
#pragma unroll
    for (int r = 0; r < 4; ++r) {
      int o = q * 4 + r;
      if (o < 5) out[e * 5 + o] = a3[r] + sm.b3v[o];
    }
  }
}

extern "C" void kernel_launch(void* const* d_in, const int* in_sizes, int n_in,
                              void* d_out, int out_size, void* d_ws, size_t ws_size,
                              hipStream_t stream) {
  const float* h    = (const float*)d_in[0];
  const float* x    = (const float*)d_in[1];
  const int* spawn  = (const int*)d_in[2];
  const int* exist  = (const int*)d_in[3];
  const float* insx = (const float*)d_in[4];
  const int* insa   = (const int*)d_in[5];
  const int* insc   = (const int*)d_in[6];
  const float* W1   = (const float*)d_in[7];
  const float* b1   = (const float*)d_in[8];
  const float* g1   = (const float*)d_in[9];
  const float* be1  = (const float*)d_in[10];
  const float* W2   = (const float*)d_in[11];
  const float* b2   = (const float*)d_in[12];
  const float* g2   = (const float*)d_in[13];
  const float* be2  = (const float*)d_in[14];
  const float* W3   = (const float*)d_in[15];
  const float* b3   = (const float*)d_in[16];
  const float* mu   = (const float*)d_in[17];
  const float* gma  = (const float*)d_in[18];

  unsigned short* w1sw = (unsigned short*)d_ws;          // 147456 el
  unsigned short* w2sw = w1sw + 147456;                  // 32768 el
  unsigned short* w3sw = w2sw + 32768;                   // 2048 el
  unsigned short* hb   = w3sw + 2048;                    // N*HID el (optional)
  const size_t need_hb = 364544ull + (size_t)NN * HIDD * 2ull;
  int use_hb = (ws_size >= need_hb) ? 1 : 0;

  prep_kern<<<use_hb ? 13212 : 712, 256, 0, stream>>>(h, W1, W2, W3, hb, w1sw, w2sw, w3sw);
  edge_head_main<<<7813, 256, 0, stream>>>(h, x, spawn, exist, insx, insa, insc,
                                           b1, g1, be1, b2, g2, be2, b3, mu, gma,
                                           w1sw, w2sw, w3sw, hb, use_hb,
                                           (float*)d_out);
}